// Round 7
// baseline (952.815 us; speedup 1.0000x reference)
//
#include <hip/hip_runtime.h>

// WaveFDTD2D, temporally-blocked: T=16 steps/launch, 32 graph launches
// (round 6 proved in-kernel cross-XCD sync forces L2 flush per poll ->
// kernel boundaries ARE the cheap grid sync). Round 7 slims round 5:
//  - receiver samples buffered in owner-thread registers (no global store
//    before per-substep barriers -> kills the vmcnt(0) drain round 5 paid)
//  - LDS carries only the 2 wave-boundary rows per wave (4 LDS instr per
//    thread-substep instead of 6; 16 KB ping-pong instead of 32 KB)
//  - cur/old packed as float2 (8 global loads + 4 stores per thread/launch)
//  - register-only rows computed first to hide the 2 ds_read latencies.
// Wave w owns 4 contiguous ext rows (4w..4w+3) at lane=ez; z-neighbors via
// DPP wave shifts; x-neighbors in registers. Trapezoid garbage never
// reaches interior/receivers (validated rounds 3-5); v2=0 pins zero BC.

#define NXd 512
#define NZd 512
#define NSTEPSd 512
#define NRECd 128
#define DT2f 1.0e-6f
#define INVf 1.0e-2f
#define TBk 16
#define TIk 32
#define EXTk 64
#define NTILEk 16

__device__ __forceinline__ float dpp_shr1(float x) {  // lane i <- lane i-1
    int v = __builtin_amdgcn_update_dpp(0, __builtin_bit_cast(int, x),
                                        0x138, 0xF, 0xF, false);  // WAVE_SHR:1
    return __builtin_bit_cast(float, v);
}
__device__ __forceinline__ float dpp_shl1(float x) {  // lane i <- lane i+1
    int v = __builtin_amdgcn_update_dpp(0, __builtin_bit_cast(int, x),
                                        0x130, 0xF, 0xF, false);  // WAVE_SHL:1
    return __builtin_bit_cast(float, v);
}

__device__ __forceinline__ float upd(float c, float o, float v2,
                                     float up, float dn) {
    float lf = dpp_shr1(c);
    float rt = dpp_shl1(c);
    float sum = (up + dn) + (lf + rt);
    float t4 = __builtin_fmaf(-4.0f, c, sum);
    float pm = __builtin_fmaf(2.0f, c, -o);
    return __builtin_fmaf(v2, t4, pm);
}

__global__ __launch_bounds__(1024) void fdtd_tblock(
    const float* __restrict__ vel,
    const float* __restrict__ source,
    const int* __restrict__ src_x, const int* __restrict__ src_z,
    const int* __restrict__ rec_x, const int* __restrict__ rec_z,
    const float2* __restrict__ Pin, float2* __restrict__ Pout,
    float* __restrict__ out, int t0)
{
    __shared__ float sb[2][32 * EXTk];   // slots 2w (row 4w), 2w+1 (row 4w+3)

    const int tid = threadIdx.x;
    const int w = tid >> 6;              // 16 waves, wave w owns rows 4w..4w+3
    const int lane = tid & 63;           // ext z coord
    const int gx0 = blockIdx.y * TIk, gz0 = blockIdx.x * TIk;
    const int ox = gx0 - TBk, oz = gz0 - TBk;
    const int gz = oz + lane;
    const bool zin = (gz >= 0 && gz < NZd);
    const int sx = *src_x, sz = *src_z;

    // ---- receiver slot scan (off the hot loop): owner thread of ext row r
    // is wave r>>2 / lane col / reg r&3. One buffered slot + 2 direct
    // (duplicate-cell receivers; essentially never occur). ----
    int s0rec = -1, s0i = 0;
    int dcnt = 0, dRec[2], dIdx[2];
    for (int j = 0; j < NRECd; ++j) {
        int rx = rec_x[j], rz = rec_z[j];
        if (rx >= gx0 && rx < gx0 + TIk && rz >= gz0 && rz < gz0 + TIk) {
            int exr = rx - ox, exc = rz - oz;
            if ((exr >> 2) == w && exc == lane) {
                if (s0rec < 0) { s0rec = j; s0i = exr & 3; }
                else if (dcnt < 2) { dRec[dcnt] = j; dIdx[dcnt] = exr & 3; ++dcnt; }
            }
        }
    }

    // ---- exact L1 cone skip (field identically 0 beyond radius t) ----
    {
        int dxm = max(0, max(ox - sx, sx - (ox + EXTk - 1)));
        int dzm = max(0, max(oz - sz, sz - (oz + EXTk - 1)));
        if (dxm + dzm > t0 + TBk + 1) {        // block-uniform, no barrier yet
            if (s0rec >= 0)
                for (int s = 0; s < TBk; ++s) out[s0rec * NSTEPSd + t0 + s] = 0.f;
            for (int k = 0; k < dcnt; ++k)
                for (int s = 0; s < TBk; ++s) out[dRec[k] * NSTEPSd + t0 + s] = 0.f;
            return;
        }
    }

    // ---- load: 4 rows/thread, cur/old packed float2, v2 folded ----
    float rCur[4], rOld[4], rV2[4];
    #pragma unroll
    for (int i = 0; i < 4; ++i) {
        const int gx = ox + 4 * w + i;
        float c = 0.f, o = 0.f, v2 = 0.f;
        if (zin && gx >= 0 && gx < NXd) {
            const int g = gx * NZd + gz;
            float2 co = Pin[g];
            c = co.x; o = co.y;
            float v = vel[g];
            v2 = v * v * (DT2f * INVf);
        }
        rCur[i] = c; rOld[i] = o; rV2[i] = v2;
    }
    sb[0][(2 * w) * EXTk + lane] = rCur[0];
    sb[0][(2 * w + 1) * EXTk + lane] = rCur[3];

    // ---- source preload (owner thread only) ----
    const int exs = sx - ox, ezs = sz - oz;
    const bool srcHere = exs >= 0 && exs < EXTk && ezs >= 0 && ezs < EXTk &&
                         w == (exs >> 2) && lane == ezs;
    const int srcI = exs & 3;
    float sv[TBk];
    if (srcHere) {
        #pragma unroll
        for (int s = 0; s < TBk; ++s) sv[s] = source[t0 + s] * DT2f;
    }

    __syncthreads();

    // ---- 16 sub-steps, fully unrolled ----
    float rv[8];
    #pragma unroll
    for (int s = 0; s < TBk; ++s) {
        const float* cb = sb[s & 1];
        float* nb = sb[(s & 1) ^ 1];
        const float up0 = (w > 0)  ? cb[(2 * w - 1) * EXTk + lane] : 0.f;
        const float dn3 = (w < 15) ? cb[(2 * w + 2) * EXTk + lane] : 0.f;
        // register-only rows first (hide the two ds_read latencies)
        float nv1 = upd(rCur[1], rOld[1], rV2[1], rCur[0], rCur[2]);
        float nv2 = upd(rCur[2], rOld[2], rV2[2], rCur[1], rCur[3]);
        float nv0 = upd(rCur[0], rOld[0], rV2[0], up0, rCur[1]);
        float nv3 = upd(rCur[3], rOld[3], rV2[3], rCur[2], dn3);
        // source injection: post-stencil, pre-recording (one thread)
        if (srcHere) {
            if (srcI == 0) nv0 += sv[s];
            else if (srcI == 1) nv1 += sv[s];
            else if (srcI == 2) nv2 += sv[s];
            else nv3 += sv[s];
        }
        rOld[0] = rCur[0]; rCur[0] = nv0;
        rOld[1] = rCur[1]; rCur[1] = nv1;
        rOld[2] = rCur[2]; rCur[2] = nv2;
        rOld[3] = rCur[3]; rCur[3] = nv3;
        nb[(2 * w) * EXTk + lane] = nv0;
        nb[(2 * w + 1) * EXTk + lane] = nv3;
        // receiver sampling from registers (post-injection), no LDS/global
        if (s0rec >= 0)
            rv[s & 7] = (s0i == 0) ? rCur[0] : (s0i == 1) ? rCur[1]
                       : (s0i == 2) ? rCur[2] : rCur[3];
        if (dcnt) {  // duplicate-cell receivers: direct store (rare)
            for (int k = 0; k < dcnt; ++k)
                out[dRec[k] * NSTEPSd + t0 + s] =
                    (dIdx[k] == 0) ? rCur[0] : (dIdx[k] == 1) ? rCur[1]
                   : (dIdx[k] == 2) ? rCur[2] : rCur[3];
        }
        __syncthreads();
        // flush receiver buffer twice per phase, just after a barrier so the
        // store ack overlaps the next substeps' compute
        if ((s == 7 || s == 15) && s0rec >= 0) {
            #pragma unroll
            for (int q = 0; q < 8; ++q)
                out[s0rec * NSTEPSd + t0 + (s - 7) + q] = rv[q];
        }
    }

    // ---- store interior (rows 16..47 = waves 4..11, lanes 16..47) ----
    if (w >= 4 && w < 12 && lane >= TBk && lane < EXTk - TBk) {
        #pragma unroll
        for (int i = 0; i < 4; ++i) {
            const int g = (ox + 4 * w + i) * NZd + gz;
            Pout[g] = make_float2(rCur[i], rOld[i]);   // cur@t0+15, old@t0+14
        }
    }
}

extern "C" void kernel_launch(void* const* d_in, const int* in_sizes, int n_in,
                              void* d_out, int out_size, void* d_ws, size_t ws_size,
                              hipStream_t stream) {
    const float* vel    = (const float*)d_in[0];
    const float* source = (const float*)d_in[1];
    const int*   src_x  = (const int*)d_in[2];
    const int*   src_z  = (const int*)d_in[3];
    const int*   rec_x  = (const int*)d_in[4];
    const int*   rec_z  = (const int*)d_in[5];
    float* out = (float*)d_out;

    const size_t F = (size_t)NXd * NZd;
    float2* PA = (float2*)d_ws;       // packed (cur, old), set A
    float2* PB = PA + F;              // set B

    // Zero both sets (4 MB; cone-zero invariant needs exact zeros).
    hipMemsetAsync(d_ws, 0, 2 * F * sizeof(float2), stream);

    dim3 grid(NTILEk, NTILEk), block(1024);
    for (int k = 0; k < NSTEPSd / TBk; ++k) {
        const float2* Pin = (k & 1) ? PB : PA;
        float2* Pout      = (k & 1) ? PA : PB;
        fdtd_tblock<<<grid, block, 0, stream>>>(vel, source, src_x, src_z,
                                                rec_x, rec_z, Pin, Pout,
                                                out, k * TBk);
    }
}

// Round 8
// 365.014 us; speedup vs baseline: 2.6104x; 2.6104x over previous
//
#include <hip/hip_runtime.h>

// WaveFDTD2D, temporally-blocked: T=16 steps/launch, 32 graph launches.
// Round 8 = round 5 (374 us, known-good) + two isolated changes:
//  - receiver samples buffered in rv[16] registers (LDS read per substep as
//    in round 5) and flushed ONCE after the loop -> no per-substep global
//    stores feeding the pre-barrier vmcnt(0) drain
//  - cur/old packed float2 (8 global load instrs, 4 stores per thread/launch)
// Round 7's 2.5x regression was the per-launch 128-iteration receiver scan
// (serialized, pre-cone-skip, every block) -- reverted to O(1) ownership.
// Wave w owns 4 contiguous ext rows (4w..4w+3) at lane=ez; z-neighbors via
// DPP wave shifts; x-neighbors in registers; boundary rows via full-field
// LDS ping-pong (receivers need the full field). Trapezoid-rim garbage
// never reaches interior/receivers (validated r3-r5); v2=0 pins zero BC.

#define NXd 512
#define NZd 512
#define NSTEPSd 512
#define NRECd 128
#define DT2f 1.0e-6f
#define INVf 1.0e-2f
#define TBk 16
#define TIk 32
#define EXTk 64
#define NTILEk 16

__device__ __forceinline__ float dpp_shr1(float x) {  // lane i <- lane i-1
    int v = __builtin_amdgcn_update_dpp(0, __builtin_bit_cast(int, x),
                                        0x138, 0xF, 0xF, false);  // WAVE_SHR:1
    return __builtin_bit_cast(float, v);
}
__device__ __forceinline__ float dpp_shl1(float x) {  // lane i <- lane i+1
    int v = __builtin_amdgcn_update_dpp(0, __builtin_bit_cast(int, x),
                                        0x130, 0xF, 0xF, false);  // WAVE_SHL:1
    return __builtin_bit_cast(float, v);
}

__global__ __launch_bounds__(1024) void fdtd_tblock(
    const float* __restrict__ vel,
    const float* __restrict__ source,
    const int* __restrict__ src_x, const int* __restrict__ src_z,
    const int* __restrict__ rec_x, const int* __restrict__ rec_z,
    const float2* __restrict__ Pin, float2* __restrict__ Pout,
    float* __restrict__ out, int t0)
{
    __shared__ float sb[2][EXTk * EXTk];

    const int tid = threadIdx.x;
    const int w   = tid >> 6;       // 16 waves, wave w owns rows 4w..4w+3
    const int ez  = tid & 63;       // lane -> ext z coord
    const int gx0 = blockIdx.y * TIk, gz0 = blockIdx.x * TIk;
    const int ox = gx0 - TBk, oz = gz0 - TBk;
    const int gz = oz + ez;
    const bool zin = (gz >= 0 && gz < NZd);
    const int sx = *src_x, sz = *src_z;

    // O(1) receiver ownership: thread r collects receiver r from LDS.
    bool rOwn = false; int rIdx = 0;
    if (tid < NRECd) {
        int rx = rec_x[tid], rz = rec_z[tid];
        rOwn = (rx >= gx0 && rx < gx0 + TIk && rz >= gz0 && rz < gz0 + TIk);
        rIdx = (rx - ox) * EXTk + (rz - oz);
    }

    // Exact L1 cone skip (field identically 0 beyond radius t).
    {
        int dxm = max(0, max(ox - sx, sx - (ox + EXTk - 1)));
        int dzm = max(0, max(oz - sz, sz - (oz + EXTk - 1)));
        if (dxm + dzm > t0 + TBk + 1) {
            if (rOwn) {
                #pragma unroll
                for (int s = 0; s < TBk; ++s)
                    out[tid * NSTEPSd + t0 + s] = 0.0f;
            }
            return;  // block-uniform: no barrier crossed
        }
    }

    // ---- Load: 4 contiguous rows/thread; cur/old packed; v2 folded ----
    float rCur[4], rOld[4], rV2i[4];
    #pragma unroll
    for (int i = 0; i < 4; ++i) {
        const int ex = 4 * w + i;
        const int gx = ox + ex;
        float c = 0.0f, o = 0.0f, v2 = 0.0f;
        if (zin && gx >= 0 && gx < NXd) {
            const int g = gx * NZd + gz;
            float2 co = Pin[g];
            c = co.x; o = co.y;
            const float v = vel[g];
            v2 = v * v * (DT2f * INVf);
        }
        rCur[i] = c; rOld[i] = o; rV2i[i] = v2;
        sb[0][ex * EXTk + ez] = c;
    }
    const int rowUp = (w == 0)  ? 0        : 4 * w - 1;
    const int rowDn = (w == 15) ? EXTk - 1 : 4 * w + 4;

    // Source preload (owner = lane ezs of wave exs>>2, register exs&3).
    const int exs = sx - ox, ezs = sz - oz;
    const bool srcHere = (exs >= 0 && exs < EXTk && ezs >= 0 && ezs < EXTk) &&
                         (tid == (((exs >> 2) << 6) | ezs));
    float sv[TBk];
    if (srcHere) {
        #pragma unroll
        for (int s = 0; s < TBk; ++s) sv[s] = source[t0 + s] * DT2f;
    }

    __syncthreads();

    // ---- 16 sub-steps, fully unrolled, no predication ----
    float rv[TBk];
    #pragma unroll
    for (int s = 0; s < TBk; ++s) {
        const float* cur = sb[s & 1];
        float* nxt = sb[(s & 1) ^ 1];
        const float up0 = cur[rowUp * EXTk + ez];   // 2 ds_read_b32 only
        const float dn3 = cur[rowDn * EXTk + ez];
        float nv[4];
        #pragma unroll
        for (int i = 0; i < 4; ++i) {
            const float up = (i == 0) ? up0 : rCur[i - 1];
            const float dn = (i == 3) ? dn3 : rCur[i + 1];
            const float lf = dpp_shr1(rCur[i]);     // z-1 neighbor (VALU)
            const float rt = dpp_shl1(rCur[i]);     // z+1 neighbor (VALU)
            const float sum = (up + dn) + (lf + rt);
            const float t4 = __builtin_fmaf(-4.0f, rCur[i], sum);
            const float pm = __builtin_fmaf(2.0f, rCur[i], -rOld[i]);
            nv[i] = __builtin_fmaf(rV2i[i], t4, pm);
        }
        #pragma unroll
        for (int i = 0; i < 4; ++i) {
            rOld[i] = rCur[i];
            rCur[i] = nv[i];
            nxt[(4 * w + i) * EXTk + ez] = nv[i];   // full field (receivers)
        }
        // Source injection (post-stencil, pre-recording).
        if (srcHere) {
            #pragma unroll
            for (int i = 0; i < 4; ++i) {
                if (i == (exs & 3)) {
                    rCur[i] += sv[s];
                    nxt[exs * EXTk + ezs] = rCur[i];
                }
            }
        }
        __syncthreads();
        // Receiver sample of field@t0+s into registers (post-injection).
        // Next substep writes the OTHER buffer -> race-free with one barrier.
        if (rOwn) rv[s] = nxt[rIdx];
    }

    // ---- Flush receiver buffer once (16 contiguous floats -> dwordx4) ----
    if (rOwn) {
        #pragma unroll
        for (int s = 0; s < TBk; ++s)
            out[tid * NSTEPSd + t0 + s] = rv[s];
    }

    // ---- Store interior (rows 16..47 = waves 4..11, lanes 16..47) ----
    if (w >= 4 && w < 12 && ez >= TBk && ez < EXTk - TBk) {
        #pragma unroll
        for (int i = 0; i < 4; ++i) {
            const int g = (ox + 4 * w + i) * NZd + gz;
            Pout[g] = make_float2(rCur[i], rOld[i]);  // cur@t0+15, old@t0+14
        }
    }
}

extern "C" void kernel_launch(void* const* d_in, const int* in_sizes, int n_in,
                              void* d_out, int out_size, void* d_ws, size_t ws_size,
                              hipStream_t stream) {
    const float* vel    = (const float*)d_in[0];
    const float* source = (const float*)d_in[1];
    const int*   src_x  = (const int*)d_in[2];
    const int*   src_z  = (const int*)d_in[3];
    const int*   rec_x  = (const int*)d_in[4];
    const int*   rec_z  = (const int*)d_in[5];
    float* out = (float*)d_out;

    const size_t F = (size_t)NXd * NZd;
    float2* PA = (float2*)d_ws;       // packed (cur, old), set A
    float2* PB = PA + F;              // set B

    // Zero both sets (4 MB; cone-zero invariant needs exact zeros).
    hipMemsetAsync(d_ws, 0, 2 * F * sizeof(float2), stream);

    dim3 grid(NTILEk, NTILEk), block(1024);
    for (int k = 0; k < NSTEPSd / TBk; ++k) {
        const float2* Pin = (k & 1) ? PB : PA;
        float2* Pout      = (k & 1) ? PA : PB;
        fdtd_tblock<<<grid, block, 0, stream>>>(vel, source, src_x, src_z,
                                                rec_x, rec_z, Pin, Pout,
                                                out, k * TBk);
    }
}